// Round 13
// baseline (668.069 us; speedup 1.0000x reference)
//
#include <hip/hip_runtime.h>
#include <hip/hip_cooperative_groups.h>
#include <math.h>

// BlockwiseEarlyExitMamba: B=128, L=64, EXIT_POS=32 -> only t<32 matter.
// v14: v13 numerics (single-bf16 activations, hi/lo weights, 2-MFMA) on the
// channel-half split grid (256 blocks = batch x half, all CUs), with v11's
// grid.sync replaced by PAIR-ONLY ticket sync (atomicAdd + volatile spin;
// flags zeroed by prep_w each launch -> replay-safe; partners bid^128 share
// an XCD -> L2-local exchange). Z GEMM runs early (zf in 16 regs) so conv
// input stays f32.
#define BATCH 128

using bf16x8 = __attribute__((ext_vector_type(8))) short;
using f32x4  = __attribute__((ext_vector_type(4))) float;
typedef unsigned short ushort_t;
typedef unsigned int   uint_t;

__device__ __forceinline__ float silu_f(float x) { return x / (1.f + __expf(-x)); }

__device__ __forceinline__ ushort_t bf16_rne(float f) {
  unsigned int u = __float_as_uint(f);
  u += 0x7FFFu + ((u >> 16) & 1u);
  return (ushort_t)(u >> 16);
}
__device__ __forceinline__ float bf16_to_f(ushort_t h) {
  return __uint_as_float(((unsigned int)h) << 16);
}
__device__ __forceinline__ void bf16_split(float f, ushort_t& hi, ushort_t& lo) {
  hi = bf16_rne(f);
  lo = bf16_rne(f - bf16_to_f(hi));
}

// single-A x split-W: a*(wh+wl) (2 MFMAs)
__device__ __forceinline__ f32x4 mfma2(bf16x8 a, bf16x8 wh, bf16x8 wl, f32x4 acc) {
  acc = __builtin_amdgcn_mfma_f32_16x16x32_bf16(a, wh, acc, 0, 0, 0);
  acc = __builtin_amdgcn_mfma_f32_16x16x32_bf16(a, wl, acc, 0, 0, 0);
  return acc;
}

// 2-tile (32 out cols) GEMM slice, 1-deep prefetch. A bf16 (LDS), W hi/lo.
template<int KSTEPS, int AP, int WP>
__device__ __forceinline__ void gemm2p(
    const ushort_t* sA, const ushort_t* wh, const ushort_t* wl, f32x4 acc[2][2]) {
  bf16x8 ca0  = *(const bf16x8*)(sA);
  bf16x8 ca1  = *(const bf16x8*)(sA + 16*AP);
  bf16x8 cw0  = *(const bf16x8*)(wh);
  bf16x8 cwl0 = *(const bf16x8*)(wl);
  bf16x8 cw1  = *(const bf16x8*)(wh + 16*WP);
  bf16x8 cwl1 = *(const bf16x8*)(wl + 16*WP);
  #pragma unroll
  for (int ks = 0; ks < KSTEPS; ++ks) {
    bf16x8 na0=ca0, na1=ca1, nw0=cw0, nwl0=cwl0, nw1=cw1, nwl1=cwl1;
    if (ks + 1 < KSTEPS) {
      int kn = (ks+1)*32;
      na0  = *(const bf16x8*)(sA + kn);
      na1  = *(const bf16x8*)(sA + 16*AP + kn);
      nw0  = *(const bf16x8*)(wh + kn);
      nwl0 = *(const bf16x8*)(wl + kn);
      nw1  = *(const bf16x8*)(wh + 16*WP + kn);
      nwl1 = *(const bf16x8*)(wl + 16*WP + kn);
    }
    acc[0][0] = mfma2(ca0, cw0, cwl0, acc[0][0]);
    acc[1][0] = mfma2(ca1, cw0, cwl0, acc[1][0]);
    acc[0][1] = mfma2(ca0, cw1, cwl1, acc[0][1]);
    acc[1][1] = mfma2(ca1, cw1, cwl1, acc[1][1]);
    ca0=na0; ca1=na1; cw0=nw0; cwl0=nwl0; cw1=nw1; cwl1=nwl1;
  }
}

// 1-tile (16 out cols) variant for xproj.
template<int KSTEPS, int AP, int WP>
__device__ __forceinline__ void gemm1p(
    const ushort_t* sA, const ushort_t* wh, const ushort_t* wl, f32x4 acc[2]) {
  bf16x8 ca0  = *(const bf16x8*)(sA);
  bf16x8 ca1  = *(const bf16x8*)(sA + 16*AP);
  bf16x8 cw0  = *(const bf16x8*)(wh);
  bf16x8 cwl0 = *(const bf16x8*)(wl);
  #pragma unroll
  for (int ks = 0; ks < KSTEPS; ++ks) {
    bf16x8 na0=ca0, na1=ca1, nw0=cw0, nwl0=cwl0;
    if (ks + 1 < KSTEPS) {
      int kn = (ks+1)*32;
      na0  = *(const bf16x8*)(sA + kn);
      na1  = *(const bf16x8*)(sA + 16*AP + kn);
      nw0  = *(const bf16x8*)(wh + kn);
      nwl0 = *(const bf16x8*)(wl + kn);
    }
    acc[0] = mfma2(ca0, cw0, cwl0, acc[0]);
    acc[1] = mfma2(ca1, cw0, cwl0, acc[1]);
    ca0=na0; ca1=na1; cw0=nw0; cwl0=nwl0;
  }
}

// ---------------- merged weight prep + flag zeroing ----------------
#define NIP (4*1024*256)
#define NOP (4*256*512)
#define NXP (4*64*512)
#define NFW (256*160)
#define NPREP (NIP+NOP+NXP+NFW)   // 1744896 = 6816*256
#define NFLAGS 1024               // 128 pairs x 8 phases
__global__ __launch_bounds__(256) void prep_w(
    const float* __restrict__ ipw, const float* __restrict__ opw,
    const float* __restrict__ xpw, const float* __restrict__ fw,
    ushort_t* __restrict__ ih, ushort_t* __restrict__ il,
    ushort_t* __restrict__ oh, ushort_t* __restrict__ ol,
    ushort_t* __restrict__ xh, ushort_t* __restrict__ xl,
    ushort_t* __restrict__ fh, ushort_t* __restrict__ fl,
    uint_t* __restrict__ flags) {
  if (blockIdx.x < 4) flags[blockIdx.x*256 + threadIdx.x] = 0;
  int i = blockIdx.x*256 + threadIdx.x;
  float v; ushort_t h, l;
  if (i < NIP) {
    v = ipw[i]; bf16_split(v, h, l); ih[i] = h; il[i] = l;
  } else if (i < NIP+NOP) {
    int j = i - NIP;
    v = opw[j]; bf16_split(v, h, l); oh[j] = h; ol[j] = l;
  } else if (i < NIP+NOP+NXP) {
    int j = i - (NIP+NOP);
    int lay = j >> 15;
    int r = (j >> 9) & 63, c = j & 511;
    v = (r < 48) ? xpw[(size_t)lay*48*512 + r*512 + c] : 0.f;
    bf16_split(v, h, l); xh[j] = h; xl[j] = l;
  } else {
    int j = i - (NIP+NOP+NXP);
    int r = j / 160, c = j - r*160;
    v = (c < 136) ? fw[r*136 + c] : 0.f;
    bf16_split(v, h, l); fh[j] = h; fl[j] = l;
  }
}

// ---------------- LDS layout (bytes) ----------------
// A: sF32 f32 [32][260]              33280  (full feat residual)
// B: sT2 f32 [32][260]               33280  (aliased sFh us [32][264]: feat bf16)
// C: sU  us  [32][264]               16896  (own-half u -> y; aliased catH)
// D: sDbc f32 [32][68]                8704  (aliased sHid f32[128])
#define OFF_A 0
#define OFF_B 33280
#define OFF_C 66560
#define OFF_D 83456
#define SMEM_TOTAL 92160

// LN of [32][256]; 16 threads/row. Reads sIn(+resid), internal barrier,
// writes sF32o + bf16 sFho.
__device__ __forceinline__ void ln_block(
    const float* sIn, const float* resid, const float* addv,
    const float* __restrict__ g, const float* __restrict__ bb,
    float* sF32o, ushort_t* sFho, int tid) {
  int row = tid >> 4, sub = tid & 15;
  float v[16];
  float s = 0.f;
  #pragma unroll
  for (int i = 0; i < 16; ++i) {
    int c = sub + 16*i;
    float t = sIn[row*260 + c];
    if (resid) t += resid[row*260 + c];
    if (addv)  t += addv[c];
    v[i] = t; s += t;
  }
  s += __shfl_xor(s, 1); s += __shfl_xor(s, 2); s += __shfl_xor(s, 4); s += __shfl_xor(s, 8);
  float mu = s * (1.f/256.f);
  float s2 = 0.f;
  #pragma unroll
  for (int i = 0; i < 16; ++i) { float dv = v[i]-mu; s2 += dv*dv; }
  s2 += __shfl_xor(s2, 1); s2 += __shfl_xor(s2, 2); s2 += __shfl_xor(s2, 4); s2 += __shfl_xor(s2, 8);
  float rs = rsqrtf(s2*(1.f/256.f) + 1e-5f);
  __syncthreads();
  #pragma unroll
  for (int i = 0; i < 16; ++i) {
    int c = sub + 16*i;
    float o = (v[i]-mu)*rs*g[c] + bb[c];
    sF32o[row*260 + c] = o;
    sFho[row*264 + c] = bf16_rne(o);
  }
}

struct KParams {
  const float *x, *ep, *ef, *ed, *plw, *plb, *piw, *pib;
  const ushort_t *fw_h, *fw_l;
  const float *fb, *tng, *tnb;
  const ushort_t *ipw_h, *ipw_l;
  const float *cw, *cb;
  const ushort_t *xpw_h, *xpw_l;
  const float *dpw, *dpb, *alog, *dsk;
  const ushort_t *opw_h, *opw_l;
  const float *lng, *lnb, *w1, *b1, *w2, *b2;
  float *gdbc;     // [256][2048] xproj partials
  float *gop;      // [256][8192] outproj partials
  uint_t *flags;   // [128][8] ticket counters (zeroed by prep_w)
  float *out;
};

// pairwise ticket sync: both blocks of a pair add 1; wait for even-base+2.
__device__ __forceinline__ void pair_sync(uint_t* flag, int tid) {
  __syncthreads();                          // all payload stores issued
  if (tid == 0) {
    __threadfence();                        // release payload to device scope
    uint_t old = atomicAdd(flag, 1u);
    uint_t target = (old & ~1u) + 2u;
    while (*((volatile uint_t*)flag) < target) __builtin_amdgcn_s_sleep(1);
  }
  __syncthreads();
  __threadfence();                          // acquire: invalidate L1 for partner data
  __syncthreads();
}

// ---------------- cooperative mega kernel ----------------
__global__ __launch_bounds__(512, 2) void mega_kernel(KParams P) {
  extern __shared__ __align__(16) char sm[];
  float*    sF32 = (float*)(sm + OFF_A);       // [32][260]
  float*    sT2  = (float*)(sm + OFF_B);       // [32][260] f32 scratch
  ushort_t* sFh  = (ushort_t*)(sm + OFF_B);    // [32][264] feat bf16 (aliases sT2)
  ushort_t* sU   = (ushort_t*)(sm + OFF_C);    // [32][264] u -> y bf16
  ushort_t* catH = (ushort_t*)(sm + OFF_C);    // [32][168] tokenizer
  float*    sDbc = (float*)(sm + OFF_D);       // [32][68]
  float*    sHid = (float*)(sm + OFF_D);       // [128] classifier

  const int tid  = threadIdx.x;
  const int bid  = blockIdx.x;
  const int b    = bid & 127;                  // batch
  const int h    = bid >> 7;                   // channel half
  const int wave = tid >> 6, lane = tid & 63;
  const int lm   = lane & 15, lq = lane >> 4;
  uint_t* pflags = P.flags + (size_t)b*8;

  // ================= tokenizer (duplicated per pair; deterministic) =========
  {
    int r = tid >> 4, cl = tid & 15;
    const float* xr = P.x + ((size_t)b*64 + r)*5;
    float x0 = xr[0], x1 = xr[1], x2 = xr[2], x3 = xr[3], x4 = xr[4];
    int proto = min(max((int)x0, 0), 255);
    int flags = min(max((int)x2, 0), 63);
    int direc = min(max((int)x4, 0), 1);
    #pragma unroll
    for (int j = 0; j < 10; ++j) {
      int c = cl + 16*j;
      float v;
      if (c < 32)       v = P.ep[proto*32 + c];
      else if (c < 64)  v = x1*P.plw[c-32] + P.plb[c-32];
      else if (c < 96)  v = P.ef[flags*32 + (c-64)];
      else if (c < 128) v = x3*P.piw[c-96] + P.pib[c-96];
      else if (c < 136) v = P.ed[direc*8 + (c-128)];
      else              v = 0.f;
      catH[r*168 + c] = bf16_rne(v);
    }
  }
  __syncthreads();
  // fusion GEMM: pre = cat @ fw^T (M=32, N=256, K=160); 8 waves x 32 cols
  {
    f32x4 acc[2][2];
    #pragma unroll
    for (int mi = 0; mi < 2; ++mi)
      #pragma unroll
      for (int nt = 0; nt < 2; ++nt) acc[mi][nt] = (f32x4){0.f,0.f,0.f,0.f};
    int nb = wave*32;
    gemm2p<5, 168, 160>(catH + lm*168 + lq*8,
                        P.fw_h + (size_t)(nb+lm)*160 + lq*8,
                        P.fw_l + (size_t)(nb+lm)*160 + lq*8, acc);
    __syncthreads();   // catH reads done (C region reused later)
    #pragma unroll
    for (int mi = 0; mi < 2; ++mi)
      #pragma unroll
      for (int nt = 0; nt < 2; ++nt)
        #pragma unroll
        for (int r2 = 0; r2 < 4; ++r2)
          sT2[(mi*16 + lq*4 + r2)*260 + nb + nt*16 + lm] = acc[mi][nt][r2];
  }
  __syncthreads();
  ln_block(sT2, nullptr, P.fb, P.tng, P.tnb, sF32, sFh, tid);
  __syncthreads();

  // ================= 4 mamba layers =================
  #pragma unroll 1
  for (int l = 0; l < 4; ++l) {
    const ushort_t* iph = P.ipw_h + (size_t)l*1024*256;
    const ushort_t* ipl2= P.ipw_l + (size_t)l*1024*256;
    const ushort_t* xph = P.xpw_h + (size_t)l*64*512;
    const ushort_t* xpl = P.xpw_l + (size_t)l*64*512;
    const ushort_t* oph = P.opw_h + (size_t)l*256*512;
    const ushort_t* opl = P.opw_l + (size_t)l*256*512;
    const ushort_t* sA = sFh + lm*264 + lq*8;

    // ---- Z GEMM first (own-half cols): zf stays in 16 regs ----
    f32x4 zf[2][2];
    #pragma unroll
    for (int mi = 0; mi < 2; ++mi)
      #pragma unroll
      for (int nt = 0; nt < 2; ++nt) zf[mi][nt] = (f32x4){0.f,0.f,0.f,0.f};
    {
      int row0 = 512 + h*256 + wave*32;
      gemm2p<8, 264, 256>(sA,
                          iph + (size_t)(row0+lm)*256 + lq*8,
                          ipl2 + (size_t)(row0+lm)*256 + lq*8, zf);
    }

    // ---- U GEMM (own-half cols) -> f32 dump to sT2 (feat dead after) ----
    {
      f32x4 acc[2][2];
      #pragma unroll
      for (int mi = 0; mi < 2; ++mi)
        #pragma unroll
        for (int nt = 0; nt < 2; ++nt) acc[mi][nt] = (f32x4){0.f,0.f,0.f,0.f};
      int row0 = h*256 + wave*32;
      gemm2p<8, 264, 256>(sA,
                          iph + (size_t)(row0+lm)*256 + lq*8,
                          ipl2 + (size_t)(row0+lm)*256 + lq*8, acc);
      __syncthreads();   // all sFh reads (Z+U, all waves) done before sT2 write
      int nb = wave*32;
      #pragma unroll
      for (int mi = 0; mi < 2; ++mi)
        #pragma unroll
        for (int nt = 0; nt < 2; ++nt)
          #pragma unroll
          for (int r2 = 0; r2 < 4; ++r2)
            sT2[(mi*16 + lq*4 + r2)*260 + nb + nt*16 + lm] = acc[mi][nt][r2];
    }
    __syncthreads();

    // ---- conv + silu: c = tid&255 local channel, hv = tid>>8 t-half ----
    {
      int c = tid & 255, hv = tid >> 8;
      int dg = h*256 + c;
      float xw[19];
      int h16 = hv*16;
      #pragma unroll
      for (int j = 0; j < 19; ++j) {
        int gt = h16 + j - 3;
        xw[j] = (gt >= 0) ? sT2[gt*260 + c] : 0.f;
      }
      const float* cwl = P.cw + (size_t)l*2048 + (size_t)dg*4;
      float w0 = cwl[0], w1c = cwl[1], w2c = cwl[2], w3 = cwl[3];
      float bias = P.cb[l*512 + dg];
      #pragma unroll
      for (int tt = 0; tt < 16; ++tt) {
        float a = bias + w0*xw[tt] + w1c*xw[tt+1] + w2c*xw[tt+2] + w3*xw[tt+3];
        sU[(h16+tt)*264 + c] = bf16_rne(silu_f(a));
      }
    }
    __syncthreads();

    // ---- xproj partial: K = own 256; 4 row-groups x 2 K-halves ----
    {
      int wg = wave & 3, kh = wave >> 2;
      f32x4 acx[2] = {(f32x4){0.f,0.f,0.f,0.f}, (f32x4){0.f,0.f,0.f,0.f}};
      gemm1p<4, 264, 512>(sU + lm*264 + kh*128 + lq*8,
                          xph + (size_t)(wg*16+lm)*512 + h*256 + kh*128 + lq*8,
                          xpl + (size_t)(wg*16+lm)*512 + h*256 + kh*128 + lq*8, acx);
      if (kh == 1) {
        #pragma unroll
        for (int mi = 0; mi < 2; ++mi)
          #pragma unroll
          for (int r2 = 0; r2 < 4; ++r2)
            sDbc[(mi*16 + lq*4 + r2)*68 + wg*16 + lm] = acx[mi][r2];
      }
      __syncthreads();
      if (kh == 0) {
        #pragma unroll
        for (int mi = 0; mi < 2; ++mi)
          #pragma unroll
          for (int r2 = 0; r2 < 4; ++r2)
            sDbc[(mi*16 + lq*4 + r2)*68 + wg*16 + lm] += acx[mi][r2];
      }
    }
    __syncthreads();
    // export own dbc partial [32][64] -> gdbc[bid]
    {
      int i0 = tid*4;
      int t = i0 >> 6, c0 = i0 & 63;
      float4 v = *(const float4*)(sDbc + t*68 + c0);
      *(float4*)(P.gdbc + (size_t)bid*2048 + i0) = v;
    }
    pair_sync(pflags + l*2, tid);
    // import partner partial, add
    {
      int i0 = tid*4;
      int t = i0 >> 6, c0 = i0 & 63;
      float4 v = *(const float4*)(P.gdbc + (size_t)(bid ^ 128)*2048 + i0);
      sDbc[t*68 + c0]     += v.x;
      sDbc[t*68 + c0 + 1] += v.y;
      sDbc[t*68 + c0 + 2] += v.z;
      sDbc[t*68 + c0 + 3] += v.w;
    }
    __syncthreads();

    // ---- dtproj + scan: thread pair per channel, n split 8+8 ----
    {
      int c = tid >> 1, p = tid & 1;
      int dg = h*256 + c;
      const float* dpwl = P.dpw + (size_t)l*8192 + (size_t)dg*16 + p*8;
      float wv[8];
      #pragma unroll
      for (int j = 0; j < 8; ++j) wv[j] = dpwl[j];
      const float* al2 = P.alog + (size_t)l*8192 + (size_t)dg*16 + p*8;
      float cc[8], hst[8];
      #pragma unroll
      for (int j = 0; j < 8; ++j) {
        cc[j] = -__expf(al2[j]) * 1.44269504f;
        hst[j] = 0.f;
      }
      float bias = P.dpb[l*512 + dg], dskv = P.dsk[l*512 + dg];
      #pragma unroll 2
      for (int t = 0; t < 32; ++t) {
        const float* rowp = sDbc + t*68;
        float raw = 0.f;
        #pragma unroll
        for (int j = 0; j < 8; ++j) raw += wv[j]*rowp[p*8 + j];
        raw += __shfl_xor(raw, 1);
        raw += bias;
        float dtv = (raw > 20.f) ? raw : __logf(1.f + __expf(raw));
        int ui = t*264 + c;
        float uv = bf16_to_f(sU[ui]);
        float du = dtv * uv;
        float yv = 0.f;
        #pragma unroll
        for (int j = 0; j < 8; ++j) {
          int n = p*8 + j;
          float en = exp2f(dtv * cc[j]);
          hst[j] = en*hst[j] + du*rowp[16 + n];
          yv += hst[j]*rowp[32 + n];
        }
        yv += __shfl_xor(yv, 1);
        if (p == 0) sU[ui] = bf16_rne(yv + uv*dskv);   // ungated y_raw
      }
    }
    __syncthreads();

    // ---- gate in fragment space: y = y_raw * silu(z) ----
    {
      int nb = wave*32;
      #pragma unroll
      for (int mi = 0; mi < 2; ++mi)
        #pragma unroll
        for (int nt = 0; nt < 2; ++nt)
          #pragma unroll
          for (int r2 = 0; r2 < 4; ++r2) {
            int t  = mi*16 + lq*4 + r2;
            int lc = nb + nt*16 + lm;
            int idx = t*264 + lc;
            float yraw = bf16_to_f(sU[idx]);
            sU[idx] = bf16_rne(yraw * silu_f(zf[mi][nt][r2]));
          }
    }
    __syncthreads();

    // ---- outproj partial: K = own 256; 8 waves x 32 out cols ----
    {
      f32x4 ao[2][2];
      #pragma unroll
      for (int mi = 0; mi < 2; ++mi)
        #pragma unroll
        for (int nt = 0; nt < 2; ++nt) ao[mi][nt] = (f32x4){0.f,0.f,0.f,0.f};
      int nbo = wave*32;
      gemm2p<8, 264, 512>(sU + lm*264 + lq*8,
                          oph + (size_t)(nbo+lm)*512 + h*256 + lq*8,
                          opl + (size_t)(nbo+lm)*512 + h*256 + lq*8, ao);
      __syncthreads();   // sU reads done; sT2 free (conv done long ago)
      #pragma unroll
      for (int mi = 0; mi < 2; ++mi)
        #pragma unroll
        for (int nt = 0; nt < 2; ++nt)
          #pragma unroll
          for (int r2 = 0; r2 < 4; ++r2) {
            int t = mi*16 + lq*4 + r2;
            int n = nbo + nt*16 + lm;
            sT2[t*260 + n] = ao[mi][nt][r2];
            P.gop[(size_t)bid*8192 + t*256 + n] = ao[mi][nt][r2];
          }
    }
    pair_sync(pflags + l*2 + 1, tid);
    // import partner outproj partial, add into sT2
    {
      int t  = tid >> 4;
      int n0 = (tid & 15) * 16;
      const float* src = P.gop + (size_t)(bid ^ 128)*8192 + t*256 + n0;
      #pragma unroll
      for (int j4 = 0; j4 < 4; ++j4) {
        float4 v = *(const float4*)(src + j4*4);
        float* dst = sT2 + t*260 + n0 + j4*4;
        dst[0] += v.x; dst[1] += v.y; dst[2] += v.z; dst[3] += v.w;
      }
    }
    __syncthreads();
    ln_block(sT2, sF32, nullptr, P.lng, P.lnb, sF32, sFh, tid);
    __syncthreads();
  }

  // ================= classifier (token 31); only h==0 writes =================
  {
    int o = tid >> 2, q = tid & 3;
    const float* fr = sF32 + 31*260;
    const float* wr = P.w1 + (size_t)o*256 + q*64;
    float s = 0.f;
    #pragma unroll 16
    for (int k = 0; k < 64; ++k) s += wr[k]*fr[q*64 + k];
    s += __shfl_xor(s, 1); s += __shfl_xor(s, 2);
    if (q == 0) sHid[o] = fmaxf(s + P.b1[o], 0.f);
    __syncthreads();
    if (h == 0 && tid < 2) {
      float oo = P.b2[tid];
      #pragma unroll 8
      for (int k = 0; k < 128; ++k) oo += P.w2[tid*128 + k]*sHid[k];
      P.out[b*2 + tid] = oo;
    }
  }
}

// ---------------- launch ----------------
extern "C" void kernel_launch(void* const* d_in, const int* in_sizes, int n_in,
                              void* d_out, int out_size, void* d_ws, size_t ws_size,
                              hipStream_t stream) {
  const float* x    = (const float*)d_in[0];
  const float* ep   = (const float*)d_in[1];
  const float* ef   = (const float*)d_in[2];
  const float* ed   = (const float*)d_in[3];
  const float* plw  = (const float*)d_in[4];
  const float* plb  = (const float*)d_in[5];
  const float* piw  = (const float*)d_in[6];
  const float* pib  = (const float*)d_in[7];
  const float* fw   = (const float*)d_in[8];
  const float* fb   = (const float*)d_in[9];
  const float* tng  = (const float*)d_in[10];
  const float* tnb  = (const float*)d_in[11];
  const float* ipw  = (const float*)d_in[12];
  const float* cw   = (const float*)d_in[13];
  const float* cb   = (const float*)d_in[14];
  const float* xpw  = (const float*)d_in[15];
  const float* dpw  = (const float*)d_in[16];
  const float* dpb  = (const float*)d_in[17];
  const float* alog = (const float*)d_in[18];
  const float* dsk  = (const float*)d_in[19];
  const float* opw  = (const float*)d_in[20];
  const float* lng  = (const float*)d_in[21];
  const float* lnb  = (const float*)d_in[22];
  const float* w1   = (const float*)d_in[23];
  const float* b1   = (const float*)d_in[24];
  const float* w2   = (const float*)d_in[25];
  const float* b2   = (const float*)d_in[26];

  ushort_t* ipw_h = (ushort_t*)d_ws;
  ushort_t* ipw_l = ipw_h + (size_t)NIP;
  ushort_t* opw_h = ipw_l + (size_t)NIP;
  ushort_t* opw_l = opw_h + (size_t)NOP;
  ushort_t* xpw_h = opw_l + (size_t)NOP;
  ushort_t* xpw_l = xpw_h + (size_t)NXP;
  ushort_t* fw_h  = xpw_l + (size_t)NXP;
  ushort_t* fw_l  = fw_h  + (size_t)NFW;
  float*    gdbc  = (float*)(fw_l + (size_t)NFW);   // 256*2048 f32
  float*    gop   = gdbc + (size_t)256*2048;        // 256*8192 f32
  uint_t*   flags = (uint_t*)(gop + (size_t)256*8192);  // 1024 u32

  static int smem_set = 0;
  if (!smem_set) {
    hipFuncSetAttribute(reinterpret_cast<const void*>(mega_kernel),
                        hipFuncAttributeMaxDynamicSharedMemorySize, SMEM_TOTAL);
    smem_set = 1;
  }

  prep_w<<<NPREP/256, 256, 0, stream>>>(ipw, opw, xpw, fw,
      ipw_h, ipw_l, opw_h, opw_l, xpw_h, xpw_l, fw_h, fw_l, flags);

  KParams P = { x, ep, ef, ed, plw, plb, piw, pib,
                fw_h, fw_l, fb, tng, tnb,
                ipw_h, ipw_l, cw, cb, xpw_h, xpw_l,
                dpw, dpb, alog, dsk, opw_h, opw_l,
                lng, lnb, w1, b1, w2, b2,
                gdbc, gop, flags, (float*)d_out };
  void* args[] = { &P };
  hipLaunchCooperativeKernel(reinterpret_cast<const void*>(mega_kernel),
                             dim3(256), dim3(512), args, SMEM_TOTAL, stream);
}

// Round 17
// 457.122 us; speedup vs baseline: 1.4615x; 1.4615x over previous
//
#include <hip/hip_runtime.h>
#include <math.h>

// BlockwiseEarlyExitMamba: B=128, L=64, EXIT_POS=32 -> only t<32 matter.
// v18: 16-wave (4 waves/SIMD) kernel, LAYOUT BUG FIXED: v15-v17 kept sU at
// pitch 264 while c ranges 0..511 (rows overlapped -> deterministic
// corruption, the real cause of absmax ~0.1; my rounding theories were
// wrong). Now: sU [32][520] bf16 aliased into sZT [32][524] f32 (v13's
// in-place conv); u_pre f32; gate via zf[2][2] registers (v14's passing
// rounding profile). LDS 133632, 1 block/CU.
#define BATCH 128

using bf16x8 = __attribute__((ext_vector_type(8))) short;
using f32x4  = __attribute__((ext_vector_type(4))) float;
typedef unsigned short ushort_t;
typedef unsigned int   uint_t;

__device__ __forceinline__ float silu_f(float x) { return x / (1.f + __expf(-x)); }

__device__ __forceinline__ ushort_t bf16_rne(float f) {
  unsigned int u = __float_as_uint(f);
  u += 0x7FFFu + ((u >> 16) & 1u);
  return (ushort_t)(u >> 16);
}
__device__ __forceinline__ float bf16_to_f(ushort_t h) {
  return __uint_as_float(((unsigned int)h) << 16);
}
__device__ __forceinline__ void bf16_split(float f, ushort_t& hi, ushort_t& lo) {
  hi = bf16_rne(f);
  lo = bf16_rne(f - bf16_to_f(hi));
}

// single-A x split-W: a*(wh+wl) (2 MFMAs)
__device__ __forceinline__ f32x4 mfma2(bf16x8 a, bf16x8 wh, bf16x8 wl, f32x4 acc) {
  acc = __builtin_amdgcn_mfma_f32_16x16x32_bf16(a, wh, acc, 0, 0, 0);
  acc = __builtin_amdgcn_mfma_f32_16x16x32_bf16(a, wl, acc, 0, 0, 0);
  return acc;
}

// 2-tile (32 out cols) GEMM, straight loop (register-light).
template<int KSTEPS, int AP, int WP>
__device__ __forceinline__ void gemm2(
    const ushort_t* sA, const ushort_t* wh, const ushort_t* wl, f32x4 acc[2][2]) {
  for (int ks = 0; ks < KSTEPS; ++ks) {
    int k0 = ks*32;
    bf16x8 a0 = *(const bf16x8*)(sA + k0);
    bf16x8 a1 = *(const bf16x8*)(sA + 16*AP + k0);
    bf16x8 w0 = *(const bf16x8*)(wh + k0);
    bf16x8 l0 = *(const bf16x8*)(wl + k0);
    bf16x8 w1 = *(const bf16x8*)(wh + 16*WP + k0);
    bf16x8 l1 = *(const bf16x8*)(wl + 16*WP + k0);
    acc[0][0] = mfma2(a0, w0, l0, acc[0][0]);
    acc[1][0] = mfma2(a1, w0, l0, acc[1][0]);
    acc[0][1] = mfma2(a0, w1, l1, acc[0][1]);
    acc[1][1] = mfma2(a1, w1, l1, acc[1][1]);
  }
}

// 1-tile (16 out cols) variant.
template<int KSTEPS, int AP, int WP>
__device__ __forceinline__ void gemm1(
    const ushort_t* sA, const ushort_t* wh, const ushort_t* wl, f32x4 acc[2]) {
  for (int ks = 0; ks < KSTEPS; ++ks) {
    int k0 = ks*32;
    bf16x8 a0 = *(const bf16x8*)(sA + k0);
    bf16x8 a1 = *(const bf16x8*)(sA + 16*AP + k0);
    bf16x8 w0 = *(const bf16x8*)(wh + k0);
    bf16x8 l0 = *(const bf16x8*)(wl + k0);
    acc[0] = mfma2(a0, w0, l0, acc[0]);
    acc[1] = mfma2(a1, w0, l0, acc[1]);
  }
}

// ---------------- merged weight prep: fp32 -> hi/lo bf16 ----------------
#define NIP (4*1024*256)
#define NOP (4*256*512)
#define NXP (4*64*512)
#define NFW (256*160)
#define NPREP (NIP+NOP+NXP+NFW)   // 1744896 = 6816*256
__global__ __launch_bounds__(256) void prep_w(
    const float* __restrict__ ipw, const float* __restrict__ opw,
    const float* __restrict__ xpw, const float* __restrict__ fw,
    ushort_t* __restrict__ ih, ushort_t* __restrict__ il,
    ushort_t* __restrict__ oh, ushort_t* __restrict__ ol,
    ushort_t* __restrict__ xh, ushort_t* __restrict__ xl,
    ushort_t* __restrict__ fh, ushort_t* __restrict__ fl) {
  int i = blockIdx.x*256 + threadIdx.x;
  float v; ushort_t h, l;
  if (i < NIP) {
    v = ipw[i]; bf16_split(v, h, l); ih[i] = h; il[i] = l;
  } else if (i < NIP+NOP) {
    int j = i - NIP;
    v = opw[j]; bf16_split(v, h, l); oh[j] = h; ol[j] = l;
  } else if (i < NIP+NOP+NXP) {
    int j = i - (NIP+NOP);
    int lay = j >> 15;
    int r = (j >> 9) & 63, c = j & 511;
    v = (r < 48) ? xpw[(size_t)lay*48*512 + r*512 + c] : 0.f;
    bf16_split(v, h, l); xh[j] = h; xl[j] = l;
  } else {
    int j = i - (NIP+NOP+NXP);
    int r = j / 160, c = j - r*160;
    v = (c < 136) ? fw[r*136 + c] : 0.f;
    bf16_split(v, h, l); fh[j] = h; fl[j] = l;
  }
}

// ---------------- LDS layout (bytes) ----------------
// A: sF32 f32 [32][260]             33280  (residual feat, persistent)
// B: union { sFh us [32][264] (feat bf16) | sT2 f32 [32][260] (pre/outproj) |
//            sDbc f32 4x[32][64] | sHid f32[128] }   33280
// C: sZT f32 [32][524]              67072  (u_pre f32; aliased:
//                                           sU us [32][520], catH us [32][168])
#define OFF_A 0
#define OFF_B 33280
#define OFF_C 66560
#define SMEM_TOTAL 133632

// LN of [32][256]; 32 threads/row (1024 threads). Reads sIn (+resid +addv);
// internal barrier; writes sF32o + bf16 sFho.
__device__ __forceinline__ void ln_block(
    const float* sIn, const float* resid, const float* addv,
    const float* __restrict__ g, const float* __restrict__ bb,
    float* sF32o, ushort_t* sFho, int tid) {
  int row = tid >> 5, sub = tid & 31;
  float v[8];
  float s = 0.f;
  #pragma unroll
  for (int i = 0; i < 8; ++i) {
    int c = sub + 32*i;
    float t = sIn[row*260 + c];
    if (resid) t += resid[row*260 + c];
    if (addv)  t += addv[c];
    v[i] = t; s += t;
  }
  s += __shfl_xor(s, 1); s += __shfl_xor(s, 2); s += __shfl_xor(s, 4);
  s += __shfl_xor(s, 8); s += __shfl_xor(s, 16);
  float mu = s * (1.f/256.f);
  float s2 = 0.f;
  #pragma unroll
  for (int i = 0; i < 8; ++i) { float dv = v[i]-mu; s2 += dv*dv; }
  s2 += __shfl_xor(s2, 1); s2 += __shfl_xor(s2, 2); s2 += __shfl_xor(s2, 4);
  s2 += __shfl_xor(s2, 8); s2 += __shfl_xor(s2, 16);
  float rs = rsqrtf(s2*(1.f/256.f) + 1e-5f);
  __syncthreads();              // sIn aliases sFho: read-before, write-after
  #pragma unroll
  for (int i = 0; i < 8; ++i) {
    int c = sub + 32*i;
    float o = (v[i]-mu)*rs*g[c] + bb[c];
    sF32o[row*260 + c] = o;
    sFho[row*264 + c] = bf16_rne(o);
  }
}

// ---------------- mega kernel: tokenizer + 4 layers + classifier ----------
__global__ __launch_bounds__(1024, 4) void mega_kernel(
    const float* __restrict__ x,
    const float* __restrict__ ep, const float* __restrict__ ef, const float* __restrict__ ed,
    const float* __restrict__ plw, const float* __restrict__ plb,
    const float* __restrict__ piw, const float* __restrict__ pib,
    const ushort_t* __restrict__ fw_h, const ushort_t* __restrict__ fw_l,
    const float* __restrict__ fb,
    const float* __restrict__ tng, const float* __restrict__ tnb,
    const ushort_t* __restrict__ ipw_h, const ushort_t* __restrict__ ipw_l,
    const float* __restrict__ cw, const float* __restrict__ cb,
    const ushort_t* __restrict__ xpw_h, const ushort_t* __restrict__ xpw_l,
    const float* __restrict__ dpw, const float* __restrict__ dpb,
    const float* __restrict__ alog, const float* __restrict__ dsk,
    const ushort_t* __restrict__ opw_h, const ushort_t* __restrict__ opw_l,
    const float* __restrict__ lng, const float* __restrict__ lnb,
    const float* __restrict__ w1, const float* __restrict__ b1,
    const float* __restrict__ w2, const float* __restrict__ b2,
    float* __restrict__ out) {
  extern __shared__ __align__(16) char sm[];
  float*    sF32 = (float*)(sm + OFF_A);       // [32][260]
  ushort_t* sFh  = (ushort_t*)(sm + OFF_B);    // [32][264] feat bf16
  float*    sT2  = (float*)(sm + OFF_B);       // [32][260] f32 scratch
  float*    sDbc = (float*)(sm + OFF_B);       // 4 x [32][64]
  float*    sHid = (float*)(sm + OFF_B);       // [128]
  float*    sZT  = (float*)(sm + OFF_C);       // [32][524] f32 u_pre staging
  ushort_t* sU   = (ushort_t*)(sm + OFF_C);    // [32][520] u -> y (bf16)
  ushort_t* catH = (ushort_t*)(sm + OFF_C);    // [32][168] tokenizer

  const int tid  = threadIdx.x;
  const int b    = blockIdx.x;
  const int wave = tid >> 6, lane = tid & 63;
  const int lm   = lane & 15, lq = lane >> 4;

  // ================= tokenizer =================
  {
    int r = tid >> 5, cl = tid & 31;
    const float* xr = x + ((size_t)b*64 + r)*5;
    float x0 = xr[0], x1 = xr[1], x2 = xr[2], x3 = xr[3], x4 = xr[4];
    int proto = min(max((int)x0, 0), 255);
    int flags = min(max((int)x2, 0), 63);
    int direc = min(max((int)x4, 0), 1);
    #pragma unroll
    for (int j = 0; j < 6; ++j) {
      int c = cl + 32*j;
      if (c < 168) {
        float v;
        if (c < 32)       v = ep[proto*32 + c];
        else if (c < 64)  v = x1*plw[c-32] + plb[c-32];
        else if (c < 96)  v = ef[flags*32 + (c-64)];
        else if (c < 128) v = x3*piw[c-96] + pib[c-96];
        else if (c < 136) v = ed[direc*8 + (c-128)];
        else              v = 0.f;
        catH[r*168 + c] = bf16_rne(v);
      }
    }
  }
  __syncthreads();
  // fusion GEMM: pre = cat @ fw^T (M=32, N=256, K=160); 16 waves x 16 cols
  {
    f32x4 acc[2] = {(f32x4){0.f,0.f,0.f,0.f}, (f32x4){0.f,0.f,0.f,0.f}};
    int nb = wave*16;
    gemm1<5, 168, 160>(catH + lm*168 + lq*8,
                       fw_h + (size_t)(nb+lm)*160 + lq*8,
                       fw_l + (size_t)(nb+lm)*160 + lq*8, acc);
    #pragma unroll
    for (int mi = 0; mi < 2; ++mi)
      #pragma unroll
      for (int r2 = 0; r2 < 4; ++r2)
        sT2[(mi*16 + lq*4 + r2)*260 + nb + lm] = acc[mi][r2];
  }
  __syncthreads();
  ln_block(sT2, nullptr, fb, tng, tnb, sF32, sFh, tid);
  __syncthreads();

  // ================= 4 mamba layers =================
  #pragma unroll 1
  for (int l = 0; l < 4; ++l) {
    const ushort_t* iph = ipw_h + (size_t)l*1024*256;
    const ushort_t* ipl2= ipw_l + (size_t)l*1024*256;
    const ushort_t* xph = xpw_h + (size_t)l*64*512;
    const ushort_t* xpl = xpw_l + (size_t)l*64*512;
    const ushort_t* oph = opw_h + (size_t)l*256*512;
    const ushort_t* opl = opw_l + (size_t)l*256*512;
    const ushort_t* sA = sFh + lm*264 + lq*8;

    // ---- Z GEMM first: zf stays in 16 regs (wave's 32 cols) ----
    f32x4 zf[2][2];
    #pragma unroll
    for (int mi = 0; mi < 2; ++mi)
      #pragma unroll
      for (int nt = 0; nt < 2; ++nt) zf[mi][nt] = (f32x4){0.f,0.f,0.f,0.f};
    {
      int row0 = 512 + wave*32;
      gemm2<8, 264, 256>(sA,
                         iph + (size_t)(row0+lm)*256 + lq*8,
                         ipl2 + (size_t)(row0+lm)*256 + lq*8, zf);
    }

    // ---- U GEMM: 16 waves x 32 cols -> u_pre f32 into sZT (C, pitch 524) ----
    {
      f32x4 acc[2][2];
      #pragma unroll
      for (int mi = 0; mi < 2; ++mi)
        #pragma unroll
        for (int nt = 0; nt < 2; ++nt) acc[mi][nt] = (f32x4){0.f,0.f,0.f,0.f};
      int row0 = wave*32;
      gemm2<8, 264, 256>(sA,
                         iph + (size_t)(row0+lm)*256 + lq*8,
                         ipl2 + (size_t)(row0+lm)*256 + lq*8, acc);
      int nb = wave*32;
      #pragma unroll
      for (int mi = 0; mi < 2; ++mi)
        #pragma unroll
        for (int nt = 0; nt < 2; ++nt)
          #pragma unroll
          for (int r2 = 0; r2 < 4; ++r2)
            sZT[(mi*16 + lq*4 + r2)*524 + nb + nt*16 + lm] = acc[mi][nt][r2];
    }
    __syncthreads();

    // ---- conv + silu: c = tid&511, hv = tid>>9; f32 window, bf16 in-place ----
    {
      int c = tid & 511, hv = tid >> 9;
      int h16 = hv*16;
      float xw[19];
      #pragma unroll
      for (int j = 0; j < 19; ++j) {
        int gt = h16 + j - 3;
        xw[j] = (gt >= 0) ? sZT[gt*524 + c] : 0.f;
      }
      __syncthreads();   // all f32 u_pre reads done before aliased bf16 write
      const float* cwl = cw + (size_t)l*2048 + (size_t)c*4;
      float w0 = cwl[0], w1c = cwl[1], w2c = cwl[2], w3 = cwl[3];
      float bias = cb[l*512 + c];
      #pragma unroll
      for (int tt = 0; tt < 16; ++tt) {
        float a = bias + w0*xw[tt] + w1c*xw[tt+1] + w2c*xw[tt+2] + w3*xw[tt+3];
        sU[(h16+tt)*520 + c] = bf16_rne(silu_f(a));
      }
    }
    __syncthreads();

    // ---- xproj: 16 waves = 4 row-groups x 4 K-quarters -> sDbc partials ----
    // (sFh dead after Z/U; region B reused as sDbc)
    {
      int wg = wave & 3, kh = wave >> 2;
      f32x4 acx[2] = {(f32x4){0.f,0.f,0.f,0.f}, (f32x4){0.f,0.f,0.f,0.f}};
      gemm1<4, 520, 512>(sU + lm*520 + kh*128 + lq*8,
                         xph + (size_t)(wg*16+lm)*512 + kh*128 + lq*8,
                         xpl + (size_t)(wg*16+lm)*512 + kh*128 + lq*8, acx);
      float* dst = sDbc + kh*2048;
      #pragma unroll
      for (int mi = 0; mi < 2; ++mi)
        #pragma unroll
        for (int r2 = 0; r2 < 4; ++r2)
          dst[(mi*16 + lq*4 + r2)*64 + wg*16 + lm] = acx[mi][r2];
    }
    __syncthreads();
    {
      int i0 = tid*2;
      #pragma unroll
      for (int j = 0; j < 2; ++j) {
        int i = i0 + j;
        sDbc[i] += sDbc[2048+i] + sDbc[4096+i] + sDbc[6144+i];
      }
    }
    __syncthreads();

    // ---- dtproj + scan (ungated): pair per channel, n split 8+8 ----
    {
      int c = tid >> 1, p = tid & 1;
      const float* dpwl = dpw + (size_t)l*8192 + (size_t)c*16 + p*8;
      float wv[8];
      #pragma unroll
      for (int j = 0; j < 8; ++j) wv[j] = dpwl[j];
      const float* al2 = alog + (size_t)l*8192 + (size_t)c*16 + p*8;
      float cc[8], hst[8];
      #pragma unroll
      for (int j = 0; j < 8; ++j) {
        cc[j] = -__expf(al2[j]) * 1.44269504f;
        hst[j] = 0.f;
      }
      float bias = dpb[l*512 + c], dskv = dsk[l*512 + c];
      #pragma unroll 2
      for (int t = 0; t < 32; ++t) {
        const float* rowp = sDbc + t*64;
        float raw = 0.f;
        #pragma unroll
        for (int j = 0; j < 8; ++j) raw += wv[j]*rowp[p*8 + j];
        raw += __shfl_xor(raw, 1);
        raw += bias;
        float dtv = (raw > 20.f) ? raw : __logf(1.f + __expf(raw));
        int ui = t*520 + c;
        float uv = bf16_to_f(sU[ui]);
        float du = dtv * uv;
        float yv = 0.f;
        #pragma unroll
        for (int j = 0; j < 8; ++j) {
          int n = p*8 + j;
          float en = exp2f(dtv * cc[j]);
          hst[j] = en*hst[j] + du*rowp[16 + n];
          yv += hst[j]*rowp[32 + n];
        }
        yv += __shfl_xor(yv, 1);
        if (p == 0) sU[ui] = bf16_rne(yv + uv*dskv);   // ungated y_raw
      }
    }
    __syncthreads();

    // ---- gate in fragment space: y = y_raw * silu(zf) ----
    {
      int nb = wave*32;
      #pragma unroll
      for (int mi = 0; mi < 2; ++mi)
        #pragma unroll
        for (int nt = 0; nt < 2; ++nt)
          #pragma unroll
          for (int r2 = 0; r2 < 4; ++r2) {
            int t = mi*16 + lq*4 + r2;
            int n = nb + nt*16 + lm;
            int idx = t*520 + n;
            float yraw = bf16_to_f(sU[idx]);
            sU[idx] = bf16_rne(yraw * silu_f(zf[mi][nt][r2]));
          }
    }
    __syncthreads();

    // ---- out_proj (256 x 512): 16 waves x 16 cols ----
    {
      f32x4 ao[2] = {(f32x4){0.f,0.f,0.f,0.f}, (f32x4){0.f,0.f,0.f,0.f}};
      int nb = wave*16;
      gemm1<16, 520, 512>(sU + lm*520 + lq*8,
                          oph + (size_t)(nb+lm)*512 + lq*8,
                          opl + (size_t)(nb+lm)*512 + lq*8, ao);
      __syncthreads();   // sDbc reads done (scan) -> sT2 (B) writable
      #pragma unroll
      for (int mi = 0; mi < 2; ++mi)
        #pragma unroll
        for (int r2 = 0; r2 < 4; ++r2)
          sT2[(mi*16 + lq*4 + r2)*260 + nb + lm] = ao[mi][r2];
    }
    __syncthreads();
    ln_block(sT2, sF32, nullptr, lng, lnb, sF32, sFh, tid);
    __syncthreads();
  }

  // ================= classifier (token 31) =================
  {
    int o = tid >> 3, q = tid & 7;
    const float* fr = sF32 + 31*260 + q*32;
    const float* wr = w1 + (size_t)o*256 + q*32;
    float s = 0.f;
    #pragma unroll 8
    for (int k = 0; k < 32; ++k) s += wr[k]*fr[k];
    s += __shfl_xor(s, 1); s += __shfl_xor(s, 2); s += __shfl_xor(s, 4);
    if (q == 0) sHid[o] = fmaxf(s + b1[o], 0.f);
    __syncthreads();
    if (tid < 2) {
      float oo = b2[tid];
      #pragma unroll 8
      for (int k = 0; k < 128; ++k) oo += w2[tid*128 + k]*sHid[k];
      out[b*2 + tid] = oo;
    }
  }
}

// ---------------- launch ----------------
extern "C" void kernel_launch(void* const* d_in, const int* in_sizes, int n_in,
                              void* d_out, int out_size, void* d_ws, size_t ws_size,
                              hipStream_t stream) {
  const float* x    = (const float*)d_in[0];
  const float* ep   = (const float*)d_in[1];
  const float* ef   = (const float*)d_in[2];
  const float* ed   = (const float*)d_in[3];
  const float* plw  = (const float*)d_in[4];
  const float* plb  = (const float*)d_in[5];
  const float* piw  = (const float*)d_in[6];
  const float* pib  = (const float*)d_in[7];
  const float* fw   = (const float*)d_in[8];
  const float* fb   = (const float*)d_in[9];
  const float* tng  = (const float*)d_in[10];
  const float* tnb  = (const float*)d_in[11];
  const float* ipw  = (const float*)d_in[12];
  const float* cw   = (const float*)d_in[13];
  const float* cb   = (const float*)d_in[14];
  const float* xpw  = (const float*)d_in[15];
  const float* dpw  = (const float*)d_in[16];
  const float* dpb  = (const float*)d_in[17];
  const float* alog = (const float*)d_in[18];
  const float* dsk  = (const float*)d_in[19];
  const float* opw  = (const float*)d_in[20];
  const float* lng  = (const float*)d_in[21];
  const float* lnb  = (const float*)d_in[22];
  const float* w1   = (const float*)d_in[23];
  const float* b1   = (const float*)d_in[24];
  const float* w2   = (const float*)d_in[25];
  const float* b2   = (const float*)d_in[26];

  ushort_t* ipw_h = (ushort_t*)d_ws;
  ushort_t* ipw_l = ipw_h + (size_t)NIP;
  ushort_t* opw_h = ipw_l + (size_t)NIP;
  ushort_t* opw_l = opw_h + (size_t)NOP;
  ushort_t* xpw_h = opw_l + (size_t)NOP;
  ushort_t* xpw_l = xpw_h + (size_t)NXP;
  ushort_t* fw_h  = xpw_l + (size_t)NXP;
  ushort_t* fw_l  = fw_h  + (size_t)NFW;

  static int smem_set = 0;
  if (!smem_set) {
    hipFuncSetAttribute(reinterpret_cast<const void*>(mega_kernel),
                        hipFuncAttributeMaxDynamicSharedMemorySize, SMEM_TOTAL);
    smem_set = 1;
  }

  prep_w<<<NPREP/256, 256, 0, stream>>>(ipw, opw, xpw, fw,
      ipw_h, ipw_l, opw_h, opw_l, xpw_h, xpw_l, fw_h, fw_l);

  mega_kernel<<<BATCH, 1024, SMEM_TOTAL, stream>>>(
      x, ep, ef, ed, plw, plb, piw, pib,
      fw_h, fw_l, fb, tng, tnb,
      ipw_h, ipw_l, cw, cb, xpw_h, xpw_l,
      dpw, dpb, alog, dsk, opw_h, opw_l,
      lng, lnb, w1, b1, w2, b2, (float*)d_out);
}

// Round 18
// 437.310 us; speedup vs baseline: 1.5277x; 1.0453x over previous
//
#include <hip/hip_runtime.h>
#include <math.h>

// BlockwiseEarlyExitMamba: B=128, L=64, EXIT_POS=32 -> only t<32 matter.
// v19: v15's all-bf16-staging design with the pitch bug fixed (520 not 264).
// v15's absmax 0.1035 was pitch corruption, not rounding — bf16 conv-input
// and bf16 gate get their first honest test here. No zf registers (gate
// reads silu(z) bf16 from LDS) and no f32 u_pre pass -> no spill at the
// 64-VGPR/1024-thread cap, one staging pass + barrier deleted.
// LDS 133120: A feat-f32 | B feat-bf16/scratch | C u/y bf16 | D silu(z) bf16.
#define BATCH 128

using bf16x8 = __attribute__((ext_vector_type(8))) short;
using f32x4  = __attribute__((ext_vector_type(4))) float;
typedef unsigned short ushort_t;
typedef unsigned int   uint_t;

__device__ __forceinline__ float silu_f(float x) { return x / (1.f + __expf(-x)); }

__device__ __forceinline__ ushort_t bf16_rne(float f) {
  unsigned int u = __float_as_uint(f);
  u += 0x7FFFu + ((u >> 16) & 1u);
  return (ushort_t)(u >> 16);
}
__device__ __forceinline__ float bf16_to_f(ushort_t h) {
  return __uint_as_float(((unsigned int)h) << 16);
}
__device__ __forceinline__ void bf16_split(float f, ushort_t& hi, ushort_t& lo) {
  hi = bf16_rne(f);
  lo = bf16_rne(f - bf16_to_f(hi));
}

// single-A x split-W: a*(wh+wl) (2 MFMAs)
__device__ __forceinline__ f32x4 mfma2(bf16x8 a, bf16x8 wh, bf16x8 wl, f32x4 acc) {
  acc = __builtin_amdgcn_mfma_f32_16x16x32_bf16(a, wh, acc, 0, 0, 0);
  acc = __builtin_amdgcn_mfma_f32_16x16x32_bf16(a, wl, acc, 0, 0, 0);
  return acc;
}

// 2-tile (32 out cols) GEMM, straight loop (register-light).
template<int KSTEPS, int AP, int WP>
__device__ __forceinline__ void gemm2(
    const ushort_t* sA, const ushort_t* wh, const ushort_t* wl, f32x4 acc[2][2]) {
  for (int ks = 0; ks < KSTEPS; ++ks) {
    int k0 = ks*32;
    bf16x8 a0 = *(const bf16x8*)(sA + k0);
    bf16x8 a1 = *(const bf16x8*)(sA + 16*AP + k0);
    bf16x8 w0 = *(const bf16x8*)(wh + k0);
    bf16x8 l0 = *(const bf16x8*)(wl + k0);
    bf16x8 w1 = *(const bf16x8*)(wh + 16*WP + k0);
    bf16x8 l1 = *(const bf16x8*)(wl + 16*WP + k0);
    acc[0][0] = mfma2(a0, w0, l0, acc[0][0]);
    acc[1][0] = mfma2(a1, w0, l0, acc[1][0]);
    acc[0][1] = mfma2(a0, w1, l1, acc[0][1]);
    acc[1][1] = mfma2(a1, w1, l1, acc[1][1]);
  }
}

// 1-tile (16 out cols) variant.
template<int KSTEPS, int AP, int WP>
__device__ __forceinline__ void gemm1(
    const ushort_t* sA, const ushort_t* wh, const ushort_t* wl, f32x4 acc[2]) {
  for (int ks = 0; ks < KSTEPS; ++ks) {
    int k0 = ks*32;
    bf16x8 a0 = *(const bf16x8*)(sA + k0);
    bf16x8 a1 = *(const bf16x8*)(sA + 16*AP + k0);
    bf16x8 w0 = *(const bf16x8*)(wh + k0);
    bf16x8 l0 = *(const bf16x8*)(wl + k0);
    acc[0] = mfma2(a0, w0, l0, acc[0]);
    acc[1] = mfma2(a1, w0, l0, acc[1]);
  }
}

// ---------------- merged weight prep: fp32 -> hi/lo bf16 ----------------
#define NIP (4*1024*256)
#define NOP (4*256*512)
#define NXP (4*64*512)
#define NFW (256*160)
#define NPREP (NIP+NOP+NXP+NFW)   // 1744896 = 6816*256
__global__ __launch_bounds__(256) void prep_w(
    const float* __restrict__ ipw, const float* __restrict__ opw,
    const float* __restrict__ xpw, const float* __restrict__ fw,
    ushort_t* __restrict__ ih, ushort_t* __restrict__ il,
    ushort_t* __restrict__ oh, ushort_t* __restrict__ ol,
    ushort_t* __restrict__ xh, ushort_t* __restrict__ xl,
    ushort_t* __restrict__ fh, ushort_t* __restrict__ fl) {
  int i = blockIdx.x*256 + threadIdx.x;
  float v; ushort_t h, l;
  if (i < NIP) {
    v = ipw[i]; bf16_split(v, h, l); ih[i] = h; il[i] = l;
  } else if (i < NIP+NOP) {
    int j = i - NIP;
    v = opw[j]; bf16_split(v, h, l); oh[j] = h; ol[j] = l;
  } else if (i < NIP+NOP+NXP) {
    int j = i - (NIP+NOP);
    int lay = j >> 15;
    int r = (j >> 9) & 63, c = j & 511;
    v = (r < 48) ? xpw[(size_t)lay*48*512 + r*512 + c] : 0.f;
    bf16_split(v, h, l); xh[j] = h; xl[j] = l;
  } else {
    int j = i - (NIP+NOP+NXP);
    int r = j / 160, c = j - r*160;
    v = (c < 136) ? fw[r*136 + c] : 0.f;
    bf16_split(v, h, l); fh[j] = h; fl[j] = l;
  }
}

// ---------------- LDS layout (bytes) ----------------
// A: sF32 f32 [32][260]             33280  (residual feat, persistent)
// B: union { sFh us [32][264] (feat bf16) | sT2 f32 [32][260] |
//            sDbc f32 4x[32][64] | sHid f32[128] }   33280
// C: sU  us [32][520]               33280  (u_pre -> u -> y; aliased catH)
// D: sZb us [32][520]               33280  (silu(z) bf16)
#define OFF_A 0
#define OFF_B 33280
#define OFF_C 66560
#define OFF_D 99840
#define SMEM_TOTAL 133120

// LN of [32][256]; 32 threads/row (1024 threads). Reads sIn (+resid +addv);
// internal barrier; writes sF32o + bf16 sFho.
__device__ __forceinline__ void ln_block(
    const float* sIn, const float* resid, const float* addv,
    const float* __restrict__ g, const float* __restrict__ bb,
    float* sF32o, ushort_t* sFho, int tid) {
  int row = tid >> 5, sub = tid & 31;
  float v[8];
  float s = 0.f;
  #pragma unroll
  for (int i = 0; i < 8; ++i) {
    int c = sub + 32*i;
    float t = sIn[row*260 + c];
    if (resid) t += resid[row*260 + c];
    if (addv)  t += addv[c];
    v[i] = t; s += t;
  }
  s += __shfl_xor(s, 1); s += __shfl_xor(s, 2); s += __shfl_xor(s, 4);
  s += __shfl_xor(s, 8); s += __shfl_xor(s, 16);
  float mu = s * (1.f/256.f);
  float s2 = 0.f;
  #pragma unroll
  for (int i = 0; i < 8; ++i) { float dv = v[i]-mu; s2 += dv*dv; }
  s2 += __shfl_xor(s2, 1); s2 += __shfl_xor(s2, 2); s2 += __shfl_xor(s2, 4);
  s2 += __shfl_xor(s2, 8); s2 += __shfl_xor(s2, 16);
  float rs = rsqrtf(s2*(1.f/256.f) + 1e-5f);
  __syncthreads();              // sIn aliases sFho: read-before, write-after
  #pragma unroll
  for (int i = 0; i < 8; ++i) {
    int c = sub + 32*i;
    float o = (v[i]-mu)*rs*g[c] + bb[c];
    sF32o[row*260 + c] = o;
    sFho[row*264 + c] = bf16_rne(o);
  }
}

// ---------------- mega kernel: tokenizer + 4 layers + classifier ----------
__global__ __launch_bounds__(1024, 4) void mega_kernel(
    const float* __restrict__ x,
    const float* __restrict__ ep, const float* __restrict__ ef, const float* __restrict__ ed,
    const float* __restrict__ plw, const float* __restrict__ plb,
    const float* __restrict__ piw, const float* __restrict__ pib,
    const ushort_t* __restrict__ fw_h, const ushort_t* __restrict__ fw_l,
    const float* __restrict__ fb,
    const float* __restrict__ tng, const float* __restrict__ tnb,
    const ushort_t* __restrict__ ipw_h, const ushort_t* __restrict__ ipw_l,
    const float* __restrict__ cw, const float* __restrict__ cb,
    const ushort_t* __restrict__ xpw_h, const ushort_t* __restrict__ xpw_l,
    const float* __restrict__ dpw, const float* __restrict__ dpb,
    const float* __restrict__ alog, const float* __restrict__ dsk,
    const ushort_t* __restrict__ opw_h, const ushort_t* __restrict__ opw_l,
    const float* __restrict__ lng, const float* __restrict__ lnb,
    const float* __restrict__ w1, const float* __restrict__ b1,
    const float* __restrict__ w2, const float* __restrict__ b2,
    float* __restrict__ out) {
  extern __shared__ __align__(16) char sm[];
  float*    sF32 = (float*)(sm + OFF_A);       // [32][260]
  ushort_t* sFh  = (ushort_t*)(sm + OFF_B);    // [32][264] feat bf16
  float*    sT2  = (float*)(sm + OFF_B);       // [32][260] f32 scratch
  float*    sDbc = (float*)(sm + OFF_B);       // 4 x [32][64]
  float*    sHid = (float*)(sm + OFF_B);       // [128]
  ushort_t* sU   = (ushort_t*)(sm + OFF_C);    // [32][520] u_pre -> u -> y
  ushort_t* catH = (ushort_t*)(sm + OFF_C);    // [32][168] tokenizer
  ushort_t* sZb  = (ushort_t*)(sm + OFF_D);    // [32][520] silu(z) bf16

  const int tid  = threadIdx.x;
  const int b    = blockIdx.x;
  const int wave = tid >> 6, lane = tid & 63;
  const int lm   = lane & 15, lq = lane >> 4;

  // ================= tokenizer =================
  {
    int r = tid >> 5, cl = tid & 31;
    const float* xr = x + ((size_t)b*64 + r)*5;
    float x0 = xr[0], x1 = xr[1], x2 = xr[2], x3 = xr[3], x4 = xr[4];
    int proto = min(max((int)x0, 0), 255);
    int flags = min(max((int)x2, 0), 63);
    int direc = min(max((int)x4, 0), 1);
    #pragma unroll
    for (int j = 0; j < 6; ++j) {
      int c = cl + 32*j;
      if (c < 168) {
        float v;
        if (c < 32)       v = ep[proto*32 + c];
        else if (c < 64)  v = x1*plw[c-32] + plb[c-32];
        else if (c < 96)  v = ef[flags*32 + (c-64)];
        else if (c < 128) v = x3*piw[c-96] + pib[c-96];
        else if (c < 136) v = ed[direc*8 + (c-128)];
        else              v = 0.f;
        catH[r*168 + c] = bf16_rne(v);
      }
    }
  }
  __syncthreads();
  // fusion GEMM: pre = cat @ fw^T (M=32, N=256, K=160); 16 waves x 16 cols
  {
    f32x4 acc[2] = {(f32x4){0.f,0.f,0.f,0.f}, (f32x4){0.f,0.f,0.f,0.f}};
    int nb = wave*16;
    gemm1<5, 168, 160>(catH + lm*168 + lq*8,
                       fw_h + (size_t)(nb+lm)*160 + lq*8,
                       fw_l + (size_t)(nb+lm)*160 + lq*8, acc);
    #pragma unroll
    for (int mi = 0; mi < 2; ++mi)
      #pragma unroll
      for (int r2 = 0; r2 < 4; ++r2)
        sT2[(mi*16 + lq*4 + r2)*260 + nb + lm] = acc[mi][r2];
  }
  __syncthreads();
  ln_block(sT2, nullptr, fb, tng, tnb, sF32, sFh, tid);
  __syncthreads();

  // ================= 4 mamba layers =================
  #pragma unroll 1
  for (int l = 0; l < 4; ++l) {
    const ushort_t* iph = ipw_h + (size_t)l*1024*256;
    const ushort_t* ipl2= ipw_l + (size_t)l*1024*256;
    const ushort_t* xph = xpw_h + (size_t)l*64*512;
    const ushort_t* xpl = xpw_l + (size_t)l*64*512;
    const ushort_t* oph = opw_h + (size_t)l*256*512;
    const ushort_t* opl = opw_l + (size_t)l*256*512;
    const ushort_t* sA = sFh + lm*264 + lq*8;

    // ---- Z GEMM: 16 waves x 32 cols -> silu(z) bf16 into sZb (region D) ----
    {
      f32x4 acc[2][2];
      #pragma unroll
      for (int mi = 0; mi < 2; ++mi)
        #pragma unroll
        for (int nt = 0; nt < 2; ++nt) acc[mi][nt] = (f32x4){0.f,0.f,0.f,0.f};
      int row0 = 512 + wave*32;
      gemm2<8, 264, 256>(sA,
                         iph + (size_t)(row0+lm)*256 + lq*8,
                         ipl2 + (size_t)(row0+lm)*256 + lq*8, acc);
      int nb = wave*32;
      #pragma unroll
      for (int mi = 0; mi < 2; ++mi)
        #pragma unroll
        for (int nt = 0; nt < 2; ++nt)
          #pragma unroll
          for (int r2 = 0; r2 < 4; ++r2) {
            int t = mi*16 + lq*4 + r2;
            int n = nb + nt*16 + lm;
            sZb[t*520 + n] = bf16_rne(silu_f(acc[mi][nt][r2]));
          }
    }

    // ---- U GEMM: 16 waves x 32 cols -> u_pre bf16 into sU (region C) ----
    {
      f32x4 acc[2][2];
      #pragma unroll
      for (int mi = 0; mi < 2; ++mi)
        #pragma unroll
        for (int nt = 0; nt < 2; ++nt) acc[mi][nt] = (f32x4){0.f,0.f,0.f,0.f};
      int row0 = wave*32;
      gemm2<8, 264, 256>(sA,
                         iph + (size_t)(row0+lm)*256 + lq*8,
                         ipl2 + (size_t)(row0+lm)*256 + lq*8, acc);
      int nb = wave*32;
      #pragma unroll
      for (int mi = 0; mi < 2; ++mi)
        #pragma unroll
        for (int nt = 0; nt < 2; ++nt)
          #pragma unroll
          for (int r2 = 0; r2 < 4; ++r2) {
            int t = mi*16 + lq*4 + r2;
            int n = nb + nt*16 + lm;
            sU[t*520 + n] = bf16_rne(acc[mi][nt][r2]);
          }
    }
    __syncthreads();

    // ---- conv + silu: c = tid&511 channel, hv = tid>>9 t-half ----
    {
      int c = tid & 511, hv = tid >> 9;
      int h16 = hv*16;
      float xw[19];
      #pragma unroll
      for (int j = 0; j < 19; ++j) {
        int gt = h16 + j - 3;
        xw[j] = (gt >= 0) ? bf16_to_f(sU[gt*520 + c]) : 0.f;
      }
      __syncthreads();    // hv=1's t13..15 reads before hv=0 overwrites them
      const float* cwl = cw + (size_t)l*2048 + (size_t)c*4;
      float w0 = cwl[0], w1c = cwl[1], w2c = cwl[2], w3 = cwl[3];
      float bias = cb[l*512 + c];
      #pragma unroll
      for (int tt = 0; tt < 16; ++tt) {
        float a = bias + w0*xw[tt] + w1c*xw[tt+1] + w2c*xw[tt+2] + w3*xw[tt+3];
        sU[(h16+tt)*520 + c] = bf16_rne(silu_f(a));
      }
    }
    __syncthreads();

    // ---- xproj: 16 waves = 4 row-groups x 4 K-quarters -> sDbc partials ----
    // (sFh dead after Z/U; region B reused as sDbc)
    {
      int wg = wave & 3, kh = wave >> 2;
      f32x4 acx[2] = {(f32x4){0.f,0.f,0.f,0.f}, (f32x4){0.f,0.f,0.f,0.f}};
      gemm1<4, 520, 512>(sU + lm*520 + kh*128 + lq*8,
                         xph + (size_t)(wg*16+lm)*512 + kh*128 + lq*8,
                         xpl + (size_t)(wg*16+lm)*512 + kh*128 + lq*8, acx);
      float* dst = sDbc + kh*2048;
      #pragma unroll
      for (int mi = 0; mi < 2; ++mi)
        #pragma unroll
        for (int r2 = 0; r2 < 4; ++r2)
          dst[(mi*16 + lq*4 + r2)*64 + wg*16 + lm] = acx[mi][r2];
    }
    __syncthreads();
    {
      int i0 = tid*2;
      #pragma unroll
      for (int j = 0; j < 2; ++j) {
        int i = i0 + j;
        sDbc[i] += sDbc[2048+i] + sDbc[4096+i] + sDbc[6144+i];
      }
    }
    __syncthreads();

    // ---- dtproj + scan + gate: thread pair per channel, n split 8+8 ----
    {
      int c = tid >> 1, p = tid & 1;
      const float* dpwl = dpw + (size_t)l*8192 + (size_t)c*16 + p*8;
      float wv[8];
      #pragma unroll
      for (int j = 0; j < 8; ++j) wv[j] = dpwl[j];
      const float* al2 = alog + (size_t)l*8192 + (size_t)c*16 + p*8;
      float cc[8], hst[8];
      #pragma unroll
      for (int j = 0; j < 8; ++j) {
        cc[j] = -__expf(al2[j]) * 1.44269504f;
        hst[j] = 0.f;
      }
      float bias = dpb[l*512 + c], dskv = dsk[l*512 + c];
      #pragma unroll 2
      for (int t = 0; t < 32; ++t) {
        const float* rowp = sDbc + t*64;
        float raw = 0.f;
        #pragma unroll
        for (int j = 0; j < 8; ++j) raw += wv[j]*rowp[p*8 + j];
        raw += __shfl_xor(raw, 1);
        raw += bias;
        float dtv = (raw > 20.f) ? raw : __logf(1.f + __expf(raw));
        int ui = t*520 + c;
        float uv = bf16_to_f(sU[ui]);
        float du = dtv * uv;
        float yv = 0.f;
        #pragma unroll
        for (int j = 0; j < 8; ++j) {
          int n = p*8 + j;
          float en = exp2f(dtv * cc[j]);
          hst[j] = en*hst[j] + du*rowp[16 + n];
          yv += hst[j]*rowp[32 + n];
        }
        yv += __shfl_xor(yv, 1);
        if (p == 0) {
          float g = (yv + uv*dskv) * bf16_to_f(sZb[ui]);
          sU[ui] = bf16_rne(g);
        }
      }
    }
    __syncthreads();

    // ---- out_proj (256 x 512): 16 waves x 16 cols ----
    {
      f32x4 ao[2] = {(f32x4){0.f,0.f,0.f,0.f}, (f32x4){0.f,0.f,0.f,0.f}};
      int nb = wave*16;
      gemm1<16, 520, 512>(sU + lm*520 + lq*8,
                          oph + (size_t)(nb+lm)*512 + lq*8,
                          opl + (size_t)(nb+lm)*512 + lq*8, ao);
      // sDbc dead (scan barrier passed); sT2 (B) writable, no conflict with sU reads
      #pragma unroll
      for (int mi = 0; mi < 2; ++mi)
        #pragma unroll
        for (int r2 = 0; r2 < 4; ++r2)
          sT2[(mi*16 + lq*4 + r2)*260 + nb + lm] = ao[mi][r2];
    }
    __syncthreads();
    ln_block(sT2, sF32, nullptr, lng, lnb, sF32, sFh, tid);
    __syncthreads();
  }

  // ================= classifier (token 31) =================
  {
    int o = tid >> 3, q = tid & 7;
    const float* fr = sF32 + 31*260 + q*32;
    const float* wr = w1 + (size_t)o*256 + q*32;
    float s = 0.f;
    #pragma unroll 8
    for (int k = 0; k < 32; ++k) s += wr[k]*fr[k];
    s += __shfl_xor(s, 1); s += __shfl_xor(s, 2); s += __shfl_xor(s, 4);
    if (q == 0) sHid[o] = fmaxf(s + b1[o], 0.f);
    __syncthreads();
    if (tid < 2) {
      float oo = b2[tid];
      #pragma unroll 8
      for (int k = 0; k < 128; ++k) oo += w2[tid*128 + k]*sHid[k];
      out[b*2 + tid] = oo;
    }
  }
}

// ---------------- launch ----------------
extern "C" void kernel_launch(void* const* d_in, const int* in_sizes, int n_in,
                              void* d_out, int out_size, void* d_ws, size_t ws_size,
                              hipStream_t stream) {
  const float* x    = (const float*)d_in[0];
  const float* ep   = (const float*)d_in[1];
  const float* ef   = (const float*)d_in[2];
  const float* ed   = (const float*)d_in[3];
  const float* plw  = (const float*)d_in[4];
  const float* plb  = (const float*)d_in[5];
  const float* piw  = (const float*)d_in[6];
  const float* pib  = (const float*)d_in[7];
  const float* fw   = (const float*)d_in[8];
  const float* fb   = (const float*)d_in[9];
  const float* tng  = (const float*)d_in[10];
  const float* tnb  = (const float*)d_in[11];
  const float* ipw  = (const float*)d_in[12];
  const float* cw   = (const float*)d_in[13];
  const float* cb   = (const float*)d_in[14];
  const float* xpw  = (const float*)d_in[15];
  const float* dpw  = (const float*)d_in[16];
  const float* dpb  = (const float*)d_in[17];
  const float* alog = (const float*)d_in[18];
  const float* dsk  = (const float*)d_in[19];
  const float* opw  = (const float*)d_in[20];
  const float* lng  = (const float*)d_in[21];
  const float* lnb  = (const float*)d_in[22];
  const float* w1   = (const float*)d_in[23];
  const float* b1   = (const float*)d_in[24];
  const float* w2   = (const float*)d_in[25];
  const float* b2   = (const float*)d_in[26];

  ushort_t* ipw_h = (ushort_t*)d_ws;
  ushort_t* ipw_l = ipw_h + (size_t)NIP;
  ushort_t* opw_h = ipw_l + (size_t)NIP;
  ushort_t* opw_l = opw_h + (size_t)NOP;
  ushort_t* xpw_h = opw_l + (size_t)NOP;
  ushort_t* xpw_l = xpw_h + (size_t)NXP;
  ushort_t* fw_h  = xpw_l + (size_t)NXP;
  ushort_t* fw_l  = fw_h  + (size_t)NFW;

  static int smem_set = 0;
  if (!smem_set) {
    hipFuncSetAttribute(reinterpret_cast<const void*>(mega_kernel),
                        hipFuncAttributeMaxDynamicSharedMemorySize, SMEM_TOTAL);
    smem_set = 1;
  }

  prep_w<<<NPREP/256, 256, 0, stream>>>(ipw, opw, xpw, fw,
      ipw_h, ipw_l, opw_h, opw_l, xpw_h, xpw_l, fw_h, fw_l);

  mega_kernel<<<BATCH, 1024, SMEM_TOTAL, stream>>>(
      x, ep, ef, ed, plw, plb, piw, pib,
      fw_h, fw_l, fb, tng, tnb,
      ipw_h, ipw_l, cw, cb, xpw_h, xpw_l,
      dpw, dpb, alog, dsk, opw_h, opw_l,
      lng, lnb, w1, b1, w2, b2, (float*)d_out);
}